// Round 3
// baseline (205.946 us; speedup 1.0000x reference)
//
#include <hip/hip_runtime.h>
#include <math.h>

#define B_   4
#define H_   496
#define W_   496
#define HW_  (H_ * W_)
#define N_   (B_ * HW_)
#define NBLK (N_ / 256)          // 3844 exactly, no tail
#define NACC 256                 // accumulator pairs in d_ws
#define POISON 0xAAAAAAAAu       // harness re-poisons d_ws to 0xAA bytes

static_assert(N_ % 256 == 0, "no tail");

// Sum over edges of P of cross(p0,p1) where [p0,p1] is the sub-segment of the
// edge inside convex CCW quad Q (Liang-Barsky, branch-free). Area(P∩Q) =
// 0.5*(clip_sum(P,Q) + clip_sum(Q,P)): the intersection boundary is exactly
// {parts of ∂P in Q} ∪ {parts of ∂Q in P}, and the line integral x dy - y dx
// is additive over pieces in any order.
__device__ __forceinline__ float clip_sum(const float px[4], const float py[4],
                                          const float qx[4], const float qy[4]) {
    float ex[4], ey[4];
#pragma unroll
    for (int i = 0; i < 4; ++i) {
        ex[i] = qx[(i + 1) & 3] - qx[i];
        ey[i] = qy[(i + 1) & 3] - qy[i];
    }
    float F[4][4];   // signed dist of P vertex k against Q edge i (>=0 inside)
#pragma unroll
    for (int i = 0; i < 4; ++i)
#pragma unroll
        for (int k = 0; k < 4; ++k)
            F[i][k] = ex[i] * (py[k] - qy[i]) - ey[i] * (px[k] - qx[i]);

    float s = 0.f;
#pragma unroll
    for (int k = 0; k < 4; ++k) {
        const int   k1 = (k + 1) & 3;
        const float ax = px[k], ay = py[k];
        const float dx = px[k1] - ax, dy = py[k1] - ay;
        float t0 = 0.f, t1 = 1.f;
#pragma unroll
        for (int i = 0; i < 4; ++i) {
            const float fa = F[i][k], fb = F[i][k1];
            const float df = fb - fa;
            const float dfs = (df == 0.f) ? 1e-30f : df;
            const float tc = __fdividef(-fa, dfs);
            t0 = fmaxf(t0, (df > 0.f) ? tc : 0.f);   // entering
            t1 = fminf(t1, (df < 0.f) ? tc : 1.f);   // exiting
            if (df == 0.f && fa < 0.f) t0 = 2.f;     // parallel & outside
        }
        const float x0 = ax + t0 * dx, y0 = ay + t0 * dy;
        const float x1 = ax + t1 * dx, y1 = ay + t1 * dy;
        const float c  = x0 * y1 - x1 * y0;
        s += (t1 > t0) ? c : 0.f;
    }
    return s;
}

__global__ __launch_bounds__(256) void iou_fused(
    const float* __restrict__ iou_pred,
    const int*   __restrict__ mask,
    const float* __restrict__ box_pred,   // [B,7,H,W]
    const float* __restrict__ box_gt,     // [B,H,W,7]
    float* __restrict__ out,
    float* __restrict__ acc)              // [2*NACC] f32 pairs + u32 counter
{
    __shared__ float sgt[256 * 7];        // this block's gt slice, staged coalesced
    __shared__ float rn[4], rd[4];
    __shared__ int lastFlag;

    const int tid  = threadIdx.x;
    const int base = blockIdx.x * 256;
    const int n    = base + tid;

    // ---- coalesced float4 staging of box_gt[base*7 .. base*7+1792) ----
    {
        const float4* g4 = (const float4*)(box_gt + (size_t)base * 7);
        float4* s4 = (float4*)sgt;
#pragma unroll
        for (int it = 0; it < 2; ++it) {
            const int idx = tid + it * 256;
            if (idx < 448) s4[idx] = g4[idx];
        }
    }
    __syncthreads();

    const int b  = n / HW_;
    const int hw = n - b * HW_;

    const float* bp = box_pred + (size_t)b * 7 * HW_ + hw;   // coalesced per channel
    const float pax = bp[0];
    const float pay = bp[1 * HW_];
    const float paz = bp[2 * HW_];
    const float pdx = bp[3 * HW_];
    const float pdy = bp[4 * HW_];
    const float pdz = bp[5 * HW_];
    const float pr  = bp[6 * HW_];

    const float* sg7 = sgt + tid * 7;     // 2-way bank alias only (free)
    const float gax = sg7[0], gay = sg7[1], gaz = sg7[2];
    const float gdx = sg7[3], gdy = sg7[4], gdz = sg7[5], gr = sg7[6];

    float sp, cp; __sincosf(pr, &sp, &cp);
    float sg, cg; __sincosf(gr, &sg, &cg);
    const float phx = 0.5f * pdx, phy = 0.5f * pdy;
    const float ghx = 0.5f * gdx, ghy = 0.5f * gdy;

    // CCW corners (reference lx=[+,-,-,+]*hx, ly=[+,+,-,-]*hy)
    float px[4], py[4], qx[4], qy[4];
    px[0] = pax + cp * phx - sp * phy;  py[0] = pay + sp * phx + cp * phy;
    px[1] = pax - cp * phx - sp * phy;  py[1] = pay - sp * phx + cp * phy;
    px[2] = pax - cp * phx + sp * phy;  py[2] = pay - sp * phx - cp * phy;
    px[3] = pax + cp * phx + sp * phy;  py[3] = pay + sp * phx - cp * phy;
    qx[0] = gax + cg * ghx - sg * ghy;  qy[0] = gay + sg * ghx + cg * ghy;
    qx[1] = gax - cg * ghx - sg * ghy;  qy[1] = gay - sg * ghx + cg * ghy;
    qx[2] = gax - cg * ghx + sg * ghy;  qy[2] = gay - sg * ghx - cg * ghy;
    qx[3] = gax + cg * ghx + sg * ghy;  qy[3] = gay + sg * ghx - cg * ghy;

    const float inter_bev = 0.5f * (clip_sum(px, py, qx, qy) +
                                    clip_sum(qx, qy, px, py));

    const float za0 = paz - 0.5f * pdz, za1 = paz + 0.5f * pdz;
    const float zb0 = gaz - 0.5f * gdz, zb1 = gaz + 0.5f * gdz;
    const float zo  = fmaxf(fminf(za1, zb1) - fmaxf(za0, zb0), 0.f);
    const float iv  = inter_bev * zo;
    const float va  = pdx * pdy * pdz;
    const float vb  = gdx * gdy * gdz;
    const float iou = iv / (va + vb - iv + 1e-7f);
    const float target = 2.f * iou - 1.f;

    const float m = (float)mask[n];
    float num = m * fabsf(iou_pred[n] - target);
    float den = m;

    // ---- block reduction ----
#pragma unroll
    for (int off = 32; off > 0; off >>= 1) {
        num += __shfl_down(num, off);
        den += __shfl_down(den, off);
    }
    if ((tid & 63) == 0) { rn[tid >> 6] = num; rd[tid >> 6] = den; }
    __syncthreads();

    // ---- device accumulation + last-block ticket ----
    if (tid == 0) {
        const float bn = rn[0] + rn[1] + rn[2] + rn[3];
        const float bd = rd[0] + rd[1] + rd[2] + rd[3];
        const int slot = blockIdx.x & (NACC - 1);
        atomicAdd(&acc[2 * slot],     bn);   // device-scope; poison bias -3e-13 is < 1 ulp of the sum
        atomicAdd(&acc[2 * slot + 1], bd);
        __threadfence();                     // release: adds visible before ticket
        const unsigned old = atomicAdd((unsigned*)(acc + 2 * NACC), 1u);
        lastFlag = (old == POISON + (unsigned)(NBLK - 1));
    }
    __syncthreads();

    if (lastFlag) {
        __threadfence();                     // acquire
        // thread t owns accumulator pair t
        float vn = __hip_atomic_load(&acc[2 * tid],     __ATOMIC_RELAXED, __HIP_MEMORY_SCOPE_AGENT);
        float vd = __hip_atomic_load(&acc[2 * tid + 1], __ATOMIC_RELAXED, __HIP_MEMORY_SCOPE_AGENT);
#pragma unroll
        for (int off = 32; off > 0; off >>= 1) {
            vn += __shfl_down(vn, off);
            vd += __shfl_down(vd, off);
        }
        if ((tid & 63) == 0) { rn[tid >> 6] = vn; rd[tid >> 6] = vd; }
        __syncthreads();
        if (tid == 0)
            out[0] = (rn[0] + rn[1] + rn[2] + rn[3]) /
                     (rd[0] + rd[1] + rd[2] + rd[3] + 1e-4f);
        // restore poison so the kernel is idempotent even without re-poisoning
        unsigned* au = (unsigned*)acc;
        __hip_atomic_store(&au[2 * tid],     POISON, __ATOMIC_RELAXED, __HIP_MEMORY_SCOPE_AGENT);
        __hip_atomic_store(&au[2 * tid + 1], POISON, __ATOMIC_RELAXED, __HIP_MEMORY_SCOPE_AGENT);
        if (tid == 0)
            __hip_atomic_store(&au[2 * NACC], POISON, __ATOMIC_RELAXED, __HIP_MEMORY_SCOPE_AGENT);
    }
}

extern "C" void kernel_launch(void* const* d_in, const int* in_sizes, int n_in,
                              void* d_out, int out_size, void* d_ws, size_t ws_size,
                              hipStream_t stream) {
    const float* iou_pred = (const float*)d_in[0];
    const int*   mask     = (const int*)  d_in[1];
    // d_in[2] = ind (unused by the layer)
    const float* box_pred = (const float*)d_in[3];
    const float* box_gt   = (const float*)d_in[4];
    float* out = (float*)d_out;
    float* acc = (float*)d_ws;   // (2*NACC + 1) * 4 bytes used

    iou_fused<<<NBLK, 256, 0, stream>>>(iou_pred, mask, box_pred, box_gt, out, acc);
}

// Round 4
// 108.413 us; speedup vs baseline: 1.8996x; 1.8996x over previous
//
#include <hip/hip_runtime.h>
#include <math.h>

#define B_   4
#define H_   496
#define W_   496
#define HW_  (H_ * W_)
#define N_   (B_ * HW_)
#define TPB  256
#define NPT  2                    // elements per thread (sequential, pipelined)
#define EPB  (TPB * NPT)          // 512 elements per block
#define NBLK (N_ / EPB)           // 1922 exactly

static_assert(N_ % EPB == 0, "no tail");

// Sum over edges of P of cross(p0,p1) where [p0,p1] is the sub-segment of the
// edge inside convex CCW quad Q (branch-free Liang-Barsky). Area(P∩Q) =
// 0.5*(clip_sum(P,Q) + clip_sum(Q,P)): the intersection boundary is exactly
// {parts of ∂P in Q} ∪ {parts of ∂Q in P}, and the line integral x dy - y dx
// is additive over pieces in any order.
//
// Degenerate-guard removal: when df==0, tc=(-fa)*rcp(df) is ±inf/NaN but both
// selects (df>0 ? : 0) and (df<0 ? : 1) discard it, so no guard is needed.
// tc is clamped to [0,1] via med3 BEFORE the max/min — equivalent for the
// strict t1>t0 emptiness test, and bounds all interpolated endpoints.
__device__ __forceinline__ float clip_sum(const float px[4], const float py[4],
                                          const float qx[4], const float qy[4]) {
    float ex[4], ey[4], c0[4];
#pragma unroll
    for (int i = 0; i < 4; ++i) {
        ex[i] = qx[(i + 1) & 3] - qx[i];
        ey[i] = qy[(i + 1) & 3] - qy[i];
        c0[i] = ex[i] * qy[i] - ey[i] * qx[i];   // F = ex*py - ey*px - c0
    }
    float F[4][4];   // signed dist of P vertex k against Q edge i (>=0 inside)
#pragma unroll
    for (int i = 0; i < 4; ++i)
#pragma unroll
        for (int k = 0; k < 4; ++k)
            F[i][k] = fmaf(ex[i], py[k], fmaf(-ey[i], px[k], -c0[i]));

    float s = 0.f;
#pragma unroll
    for (int k = 0; k < 4; ++k) {
        const int   k1 = (k + 1) & 3;
        const float ax = px[k], ay = py[k];
        const float dx = px[k1] - ax, dy = py[k1] - ay;
        float t0 = 0.f, t1 = 1.f;
#pragma unroll
        for (int i = 0; i < 4; ++i) {
            const float fa = F[i][k], fb = F[i][k1];
            const float df = fb - fa;
            const float tc = -fa * __builtin_amdgcn_rcpf(df);
            const float tl = __builtin_amdgcn_fmed3f(tc, 0.f, 1.f);
            t0 = fmaxf(t0, (df > 0.f) ? tl : 0.f);   // entering
            t1 = fminf(t1, (df < 0.f) ? tl : 1.f);   // exiting
        }
        const float x0 = fmaf(t0, dx, ax), y0 = fmaf(t0, dy, ay);
        const float x1 = fmaf(t1, dx, ax), y1 = fmaf(t1, dy, ay);
        const float c  = fmaf(x0, y1, -x1 * y0);
        s += (t1 > t0) ? c : 0.f;
    }
    return s;
}

__device__ __forceinline__ void iou_elem(
    int n, const float* __restrict__ iou_pred, const int* __restrict__ mask,
    const float* __restrict__ box_pred, const float* __restrict__ sg7,
    float& num, float& den)
{
    const int b  = n / HW_;
    const int hw = n - b * HW_;

    const float* bp = box_pred + (size_t)b * 7 * HW_ + hw;   // coalesced per channel
    const float pax = bp[0];
    const float pay = bp[1 * HW_];
    const float paz = bp[2 * HW_];
    const float pdx = bp[3 * HW_];
    const float pdy = bp[4 * HW_];
    const float pdz = bp[5 * HW_];
    const float pr  = bp[6 * HW_];

    const float gax = sg7[0], gay = sg7[1], gaz = sg7[2];
    const float gdx = sg7[3], gdy = sg7[4], gdz = sg7[5], gr = sg7[6];

    float sp, cp; __sincosf(pr, &sp, &cp);
    float sg, cg; __sincosf(gr, &sg, &cg);
    const float phx = 0.5f * pdx, phy = 0.5f * pdy;
    const float ghx = 0.5f * gdx, ghy = 0.5f * gdy;

    // CCW corners (reference lx=[+,-,-,+]*hx, ly=[+,+,-,-]*hy)
    float px[4], py[4], qx[4], qy[4];
    px[0] = pax + cp * phx - sp * phy;  py[0] = pay + sp * phx + cp * phy;
    px[1] = pax - cp * phx - sp * phy;  py[1] = pay - sp * phx + cp * phy;
    px[2] = pax - cp * phx + sp * phy;  py[2] = pay - sp * phx - cp * phy;
    px[3] = pax + cp * phx + sp * phy;  py[3] = pay + sp * phx - cp * phy;
    qx[0] = gax + cg * ghx - sg * ghy;  qy[0] = gay + sg * ghx + cg * ghy;
    qx[1] = gax - cg * ghx - sg * ghy;  qy[1] = gay - sg * ghx + cg * ghy;
    qx[2] = gax - cg * ghx + sg * ghy;  qy[2] = gay - sg * ghx - cg * ghy;
    qx[3] = gax + cg * ghx + sg * ghy;  qy[3] = gay + sg * ghx - cg * ghy;

    const float inter_bev = 0.5f * (clip_sum(px, py, qx, qy) +
                                    clip_sum(qx, qy, px, py));

    const float za0 = paz - 0.5f * pdz, za1 = paz + 0.5f * pdz;
    const float zb0 = gaz - 0.5f * gdz, zb1 = gaz + 0.5f * gdz;
    const float zo  = fmaxf(fminf(za1, zb1) - fmaxf(za0, zb0), 0.f);
    const float iv  = inter_bev * zo;
    const float va  = pdx * pdy * pdz;
    const float vb  = gdx * gdy * gdz;
    const float iou = iv / (va + vb - iv + 1e-7f);
    const float target = 2.f * iou - 1.f;

    const float m = (float)mask[n];
    num += m * fabsf(iou_pred[n] - target);
    den += m;
}

__global__ __launch_bounds__(TPB) void iou_main(
    const float* __restrict__ iou_pred,
    const int*   __restrict__ mask,
    const float* __restrict__ box_pred,   // [B,7,H,W]
    const float* __restrict__ box_gt,     // [B,H,W,7]
    float2* __restrict__ ws)              // [NBLK] block partials (num, den)
{
    __shared__ float sgt[EPB * 7];        // both chunks' gt slice, staged coalesced
    __shared__ float rn[4], rd[4];

    const int tid  = threadIdx.x;
    const int base = blockIdx.x * EPB;

    // coalesced float4 staging of box_gt[base*7 .. base*7 + EPB*7)
    {
        const float4* g4 = (const float4*)(box_gt + (size_t)base * 7);
        float4* s4 = (float4*)sgt;
#pragma unroll
        for (int it = 0; it < (EPB * 7) / (4 * TPB); ++it)    // 896/256 = 3.5 -> 3 full
            s4[tid + it * TPB] = g4[tid + it * TPB];
        const int idx = tid + 3 * TPB;
        if (idx < (EPB * 7) / 4) s4[idx] = g4[idx];
    }
    __syncthreads();

    float num = 0.f, den = 0.f;
#pragma unroll
    for (int e = 0; e < NPT; ++e) {
        const int n = base + e * TPB + tid;
        iou_elem(n, iou_pred, mask, box_pred, sgt + (e * TPB + tid) * 7, num, den);
    }

    // wave(64) shuffle reduction, then cross-wave via LDS
#pragma unroll
    for (int off = 32; off > 0; off >>= 1) {
        num += __shfl_down(num, off);
        den += __shfl_down(den, off);
    }
    if ((tid & 63) == 0) { rn[tid >> 6] = num; rd[tid >> 6] = den; }
    __syncthreads();
    if (tid == 0)
        ws[blockIdx.x] = make_float2(rn[0] + rn[1] + rn[2] + rn[3],
                                     rd[0] + rd[1] + rd[2] + rd[3]);
}

__global__ __launch_bounds__(TPB) void iou_fin(const float2* __restrict__ ws,
                                               float* __restrict__ out) {
    __shared__ float rn[4], rd[4];
    float sn = 0.f, sd = 0.f;
    for (int i = threadIdx.x; i < NBLK; i += TPB) {
        const float2 v = ws[i];
        sn += v.x;
        sd += v.y;
    }
#pragma unroll
    for (int off = 32; off > 0; off >>= 1) {
        sn += __shfl_down(sn, off);
        sd += __shfl_down(sd, off);
    }
    const int tid = threadIdx.x;
    if ((tid & 63) == 0) { rn[tid >> 6] = sn; rd[tid >> 6] = sd; }
    __syncthreads();
    if (tid == 0)
        out[0] = (rn[0] + rn[1] + rn[2] + rn[3]) /
                 (rd[0] + rd[1] + rd[2] + rd[3] + 1e-4f);
}

extern "C" void kernel_launch(void* const* d_in, const int* in_sizes, int n_in,
                              void* d_out, int out_size, void* d_ws, size_t ws_size,
                              hipStream_t stream) {
    const float* iou_pred = (const float*)d_in[0];
    const int*   mask     = (const int*)  d_in[1];
    // d_in[2] = ind (unused by the layer)
    const float* box_pred = (const float*)d_in[3];
    const float* box_gt   = (const float*)d_in[4];
    float*  out = (float*)d_out;
    float2* ws  = (float2*)d_ws;   // NBLK float2 partials, plain stores (no init)

    iou_main<<<NBLK, TPB, 0, stream>>>(iou_pred, mask, box_pred, box_gt, ws);
    iou_fin<<<1, TPB, 0, stream>>>(ws, out);
}

// Round 5
// 106.102 us; speedup vs baseline: 1.9410x; 1.0218x over previous
//
#include <hip/hip_runtime.h>
#include <math.h>

#define B_   4
#define H_   496
#define W_   496
#define HW_  (H_ * W_)
#define N_   (B_ * HW_)
#define TPB  256
#define NPT  2                    // elements per thread
#define EPB  (TPB * NPT)          // 512 elements per block
#define NBLK (N_ / EPB)           // 1922 exactly

static_assert(N_ % EPB == 0, "no tail");

// Clip segment (xk,yk)+t*(dx,dy), t in [0,1], against axis box [-hx,hx]x[-hy,hy].
// Returns max(t1-t0, 0). rdx=rcp(dx), rdy=rcp(dy) (signed, may be +-inf).
// When a direction component is exactly +-0, both its selects gate false
// (IEEE: -0<0 and -0>0 are false), so inf/NaN tc never escapes. Exactly-
// parallel-and-outside edges are the same measure-zero hole R1/R3 carried.
__device__ __forceinline__ float edge_delta(float xk, float yk,
                                            float dx, float dy,
                                            float rdx, float rdy,
                                            float hx, float hy) {
    float t0 = 0.f, t1 = 1.f, tl;
    tl = __builtin_amdgcn_fmed3f((hy - yk) * rdy, 0.f, 1.f);   // y <= hy
    t0 = fmaxf(t0, (dy < 0.f) ? tl : 0.f);
    t1 = fminf(t1, (dy > 0.f) ? tl : 1.f);
    tl = __builtin_amdgcn_fmed3f(-(xk + hx) * rdx, 0.f, 1.f);  // x >= -hx
    t0 = fmaxf(t0, (dx > 0.f) ? tl : 0.f);
    t1 = fminf(t1, (dx < 0.f) ? tl : 1.f);
    tl = __builtin_amdgcn_fmed3f(-(yk + hy) * rdy, 0.f, 1.f);  // y >= -hy
    t0 = fmaxf(t0, (dy > 0.f) ? tl : 0.f);
    t1 = fminf(t1, (dy < 0.f) ? tl : 1.f);
    tl = __builtin_amdgcn_fmed3f((hx - xk) * rdx, 0.f, 1.f);   // x <= hx
    t0 = fmaxf(t0, (dx < 0.f) ? tl : 0.f);
    t1 = fminf(t1, (dx > 0.f) ? tl : 1.f);
    return fmaxf(t1 - t0, 0.f);
}

__device__ __forceinline__ void iou_elem(
    int n, const float* __restrict__ iou_pred, const int* __restrict__ mask,
    const float* __restrict__ box_pred, const float* __restrict__ sg7,
    float& num, float& den)
{
    const int b  = n / HW_;
    const int hw = n - b * HW_;

    const float* bp = box_pred + (size_t)b * 7 * HW_ + hw;   // coalesced per channel
    const float pax = bp[0];
    const float pay = bp[1 * HW_];
    const float paz = bp[2 * HW_];
    const float pdx = bp[3 * HW_];
    const float pdy = bp[4 * HW_];
    const float pdz = bp[5 * HW_];
    const float pr  = bp[6 * HW_];

    const float gax = sg7[0], gay = sg7[1], gaz = sg7[2];
    const float gdx = sg7[3], gdy = sg7[4], gdz = sg7[5], gr = sg7[6];

    float sp, cp; __sincosf(pr, &sp, &cp);
    float sg, cg; __sincosf(gr, &sg, &cg);
    // relative pose of pred in gt's local frame (gt axis-aligned there)
    const float cth = fmaf(cp, cg,  sp * sg);   // cos(pr-gr)
    const float sth = fmaf(sp, cg, -cp * sg);   // sin(pr-gr)
    const float wx = pax - gax, wy = pay - gay;
    const float cx = fmaf(cg, wx,  sg * wy);
    const float cy = fmaf(cg, wy, -sg * wx);

    const float phx = 0.5f * pdx, phy = 0.5f * pdy;
    const float ghx = 0.5f * gdx, ghy = 0.5f * gdy;

    // pred corners in gt frame: p[j] = c + R(th)*([+,-,-,+]phx, [+,+,-,-]phy)
    const float a1 = cth * phx, b1 = sth * phx;
    const float a2 = sth * phy, b2 = cth * phy;
    const float e1 = a1 - a2, e2 = a1 + a2;
    const float f1 = b1 + b2, f2 = b1 - b2;
    const float px0 = cx + e1, py0 = cy + f1;
    const float px1 = cx - e2, py1 = cy - f2;
    const float px2 = cx - e1, py2 = cy - f1;
    const float px3 = cx + e2, py3 = cy + f2;

    // rect edge dirs: +-2(a1,b1), +-(2a2,-2b2) -> only 4 distinct rcps
    const float ta1 = a1 + a1, tb1 = b1 + b1;
    const float ta2 = a2 + a2, tb2 = b2 + b2;
    const float ra1 = __builtin_amdgcn_rcpf(ta1);
    const float rb1 = __builtin_amdgcn_rcpf(tb1);
    const float ra2 = __builtin_amdgcn_rcpf(ta2);
    const float rb2 = __builtin_amdgcn_rcpf(tb2);

    // Half 1: pred edges clipped by gt box. Piece contribution to area:
    // 0.5*(x0*y1 - x1*y0) == Delta * 0.5*cross(p_k, d_k)  (exact identity)
    float inter;
    {
        const float d0 = edge_delta(px0, py0, -ta1, -tb1, -ra1, -rb1, ghx, ghy);
        const float d1 = edge_delta(px1, py1,  ta2, -tb2,  ra2, -rb2, ghx, ghy);
        const float d2 = edge_delta(px2, py2,  ta1,  tb1,  ra1,  rb1, ghx, ghy);
        const float d3 = edge_delta(px3, py3, -ta2,  tb2, -ra2,  rb2, ghx, ghy);
        inter =        d0 * fmaf(a1, py0, -b1 * px0);
        inter = fmaf(  d1, -fmaf(b2, px1,  a2 * py1), inter);
        inter = fmaf(  d2,  fmaf(b1, px2, -a1 * py2), inter);
        inter = fmaf(  d3,  fmaf(b2, px3,  a2 * py3), inter);
    }

    // Half 2: gt edges clipped by pred box, t-params computed in pred's local
    // frame (t is frame-invariant). gt edges are axis-aligned in gt frame, so
    // each piece contributes ghx*ghy*Delta to the area.
    {
        const float A  = cth * ghx, Dv = sth * ghx;
        const float Bq = sth * ghy, Ev = cth * ghy;
        const float Cc = fmaf(cth, cx,  sth * cy);
        const float Gf = fmaf(sth, cx, -cth * cy);
        const float g1 = A + Bq,  g2 = A - Bq;
        const float h1 = Ev - Dv, h2 = Ev + Dv;
        const float u0 =  g1 - Cc, v0 =  h1 + Gf;
        const float u1 = -g2 - Cc, v1 =  h2 + Gf;
        const float u2 = -g1 - Cc, v2 = -h1 + Gf;
        const float u3 =  g2 - Cc, v3 = -h2 + Gf;

        const float tA = A + A,  tD = Dv + Dv;
        const float tB = Bq + Bq, tE = Ev + Ev;
        const float rA = __builtin_amdgcn_rcpf(tA);
        const float rD = __builtin_amdgcn_rcpf(tD);
        const float rB = __builtin_amdgcn_rcpf(tB);
        const float rE = __builtin_amdgcn_rcpf(tE);

        float sq;
        sq  = edge_delta(u0, v0, -tA,  tD, -rA,  rD, phx, phy);
        sq += edge_delta(u1, v1, -tB, -tE, -rB, -rE, phx, phy);
        sq += edge_delta(u2, v2,  tA, -tD,  rA, -rD, phx, phy);
        sq += edge_delta(u3, v3,  tB,  tE,  rB,  rE, phx, phy);
        inter = fmaf(ghx * ghy, sq, inter);
    }

    const float za0 = paz - 0.5f * pdz, za1 = paz + 0.5f * pdz;
    const float zb0 = gaz - 0.5f * gdz, zb1 = gaz + 0.5f * gdz;
    const float zo  = fmaxf(fminf(za1, zb1) - fmaxf(za0, zb0), 0.f);
    const float iv  = inter * zo;
    const float va  = pdx * pdy * pdz;
    const float vb  = gdx * gdy * gdz;
    const float iou = iv / (va + vb - iv + 1e-7f);
    const float target = 2.f * iou - 1.f;

    const float m = (float)mask[n];
    num += m * fabsf(iou_pred[n] - target);
    den += m;
}

__global__ __launch_bounds__(TPB) void iou_main(
    const float* __restrict__ iou_pred,
    const int*   __restrict__ mask,
    const float* __restrict__ box_pred,   // [B,7,H,W]
    const float* __restrict__ box_gt,     // [B,H,W,7]
    float2* __restrict__ ws)              // [NBLK] block partials (num, den)
{
    __shared__ float sgt[EPB * 7];        // block's gt slice, staged coalesced
    __shared__ float rn[4], rd[4];

    const int tid  = threadIdx.x;
    const int base = blockIdx.x * EPB;

    {
        const float4* g4 = (const float4*)(box_gt + (size_t)base * 7);
        float4* s4 = (float4*)sgt;
#pragma unroll
        for (int it = 0; it < 3; ++it)                 // 896 float4 total
            s4[tid + it * TPB] = g4[tid + it * TPB];
        const int idx = tid + 3 * TPB;
        if (idx < (EPB * 7) / 4) s4[idx] = g4[idx];
    }
    __syncthreads();

    float num = 0.f, den = 0.f;
#pragma unroll
    for (int e = 0; e < NPT; ++e) {
        const int n = base + e * TPB + tid;
        iou_elem(n, iou_pred, mask, box_pred, sgt + (e * TPB + tid) * 7, num, den);
    }

#pragma unroll
    for (int off = 32; off > 0; off >>= 1) {
        num += __shfl_down(num, off);
        den += __shfl_down(den, off);
    }
    if ((tid & 63) == 0) { rn[tid >> 6] = num; rd[tid >> 6] = den; }
    __syncthreads();
    if (tid == 0)
        ws[blockIdx.x] = make_float2(rn[0] + rn[1] + rn[2] + rn[3],
                                     rd[0] + rd[1] + rd[2] + rd[3]);
}

__global__ __launch_bounds__(TPB) void iou_fin(const float2* __restrict__ ws,
                                               float* __restrict__ out) {
    __shared__ float rn[4], rd[4];
    float sn = 0.f, sd = 0.f;
    for (int i = threadIdx.x; i < NBLK; i += TPB) {
        const float2 v = ws[i];
        sn += v.x;
        sd += v.y;
    }
#pragma unroll
    for (int off = 32; off > 0; off >>= 1) {
        sn += __shfl_down(sn, off);
        sd += __shfl_down(sd, off);
    }
    const int tid = threadIdx.x;
    if ((tid & 63) == 0) { rn[tid >> 6] = sn; rd[tid >> 6] = sd; }
    __syncthreads();
    if (tid == 0)
        out[0] = (rn[0] + rn[1] + rn[2] + rn[3]) /
                 (rd[0] + rd[1] + rd[2] + rd[3] + 1e-4f);
}

extern "C" void kernel_launch(void* const* d_in, const int* in_sizes, int n_in,
                              void* d_out, int out_size, void* d_ws, size_t ws_size,
                              hipStream_t stream) {
    const float* iou_pred = (const float*)d_in[0];
    const int*   mask     = (const int*)  d_in[1];
    // d_in[2] = ind (unused by the layer)
    const float* box_pred = (const float*)d_in[3];
    const float* box_gt   = (const float*)d_in[4];
    float*  out = (float*)d_out;
    float2* ws  = (float2*)d_ws;   // NBLK float2 partials, plain stores

    iou_main<<<NBLK, TPB, 0, stream>>>(iou_pred, mask, box_pred, box_gt, ws);
    iou_fin<<<1, TPB, 0, stream>>>(ws, out);
}

// Round 6
// 105.839 us; speedup vs baseline: 1.9458x; 1.0025x over previous
//
#include <hip/hip_runtime.h>
#include <math.h>

#define B_   4
#define H_   496
#define W_   496
#define HW_  (H_ * W_)
#define N_   (B_ * HW_)
#define TPB  256
#define NPT  4                    // consecutive elements per thread (vector loads)
#define EPB  (TPB * NPT)          // 1024 elements per block
#define NBLK (N_ / EPB)           // 961 exactly

static_assert(N_ % EPB == 0, "no tail");
static_assert(HW_ % NPT == 0, "thread quad must not straddle batch b");

union F4 { float4 v; float a[4]; };
union I4 { int4 v; int a[4]; };

// Clip segment (xk,yk)+t*(dx,dy), t in [0,1], against axis box [-hx,hx]x[-hy,hy].
// Returns max(t1-t0, 0). rdx=rcp(dx), rdy=rcp(dy) (signed, may be +-inf).
// If a direction component is exactly +-0 both its selects gate false, so
// inf/NaN tc never escapes (same measure-zero parallel-edge caveat as R1-R4).
__device__ __forceinline__ float edge_delta(float xk, float yk,
                                            float dx, float dy,
                                            float rdx, float rdy,
                                            float hx, float hy) {
    float t0 = 0.f, t1 = 1.f, tl;
    tl = __builtin_amdgcn_fmed3f((hy - yk) * rdy, 0.f, 1.f);   // y <= hy
    t0 = fmaxf(t0, (dy < 0.f) ? tl : 0.f);
    t1 = fminf(t1, (dy > 0.f) ? tl : 1.f);
    tl = __builtin_amdgcn_fmed3f(-(xk + hx) * rdx, 0.f, 1.f);  // x >= -hx
    t0 = fmaxf(t0, (dx > 0.f) ? tl : 0.f);
    t1 = fminf(t1, (dx < 0.f) ? tl : 1.f);
    tl = __builtin_amdgcn_fmed3f(-(yk + hy) * rdy, 0.f, 1.f);  // y >= -hy
    t0 = fmaxf(t0, (dy > 0.f) ? tl : 0.f);
    t1 = fminf(t1, (dy < 0.f) ? tl : 1.f);
    tl = __builtin_amdgcn_fmed3f((hx - xk) * rdx, 0.f, 1.f);   // x <= hx
    t0 = fmaxf(t0, (dx < 0.f) ? tl : 0.f);
    t1 = fminf(t1, (dx > 0.f) ? tl : 1.f);
    return fmaxf(t1 - t0, 0.f);
}

// One element's IoU-loss terms from 7 pred + 7 gt params (gt-local-frame method).
__device__ __forceinline__ void iou_elem(
    float pax, float pay, float paz, float pdx, float pdy, float pdz, float pr,
    float gax, float gay, float gaz, float gdx, float gdy, float gdz, float gr,
    float ip, float m, float& num, float& den)
{
    float sp, cp; __sincosf(pr, &sp, &cp);
    float sg, cg; __sincosf(gr, &sg, &cg);
    const float cth = fmaf(cp, cg,  sp * sg);   // cos(pr-gr)
    const float sth = fmaf(sp, cg, -cp * sg);   // sin(pr-gr)
    const float wx = pax - gax, wy = pay - gay;
    const float cx = fmaf(cg, wx,  sg * wy);
    const float cy = fmaf(cg, wy, -sg * wx);

    const float phx = 0.5f * pdx, phy = 0.5f * pdy;
    const float ghx = 0.5f * gdx, ghy = 0.5f * gdy;

    // pred corners in gt frame: c + R(th)*([+,-,-,+]phx, [+,+,-,-]phy)
    const float a1 = cth * phx, b1 = sth * phx;
    const float a2 = sth * phy, b2 = cth * phy;
    const float e1 = a1 - a2, e2 = a1 + a2;
    const float f1 = b1 + b2, f2 = b1 - b2;
    const float px0 = cx + e1, py0 = cy + f1;
    const float px1 = cx - e2, py1 = cy - f2;
    const float px2 = cx - e1, py2 = cy - f1;
    const float px3 = cx + e2, py3 = cy + f2;

    const float ta1 = a1 + a1, tb1 = b1 + b1;
    const float ta2 = a2 + a2, tb2 = b2 + b2;
    const float ra1 = __builtin_amdgcn_rcpf(ta1);
    const float rb1 = __builtin_amdgcn_rcpf(tb1);
    const float ra2 = __builtin_amdgcn_rcpf(ta2);
    const float rb2 = __builtin_amdgcn_rcpf(tb2);

    // Half 1: pred edges vs gt box. Piece area = Delta * 0.5*cross(p_k, d_k).
    float inter;
    {
        const float d0 = edge_delta(px0, py0, -ta1, -tb1, -ra1, -rb1, ghx, ghy);
        const float d1 = edge_delta(px1, py1,  ta2, -tb2,  ra2, -rb2, ghx, ghy);
        const float d2 = edge_delta(px2, py2,  ta1,  tb1,  ra1,  rb1, ghx, ghy);
        const float d3 = edge_delta(px3, py3, -ta2,  tb2, -ra2,  rb2, ghx, ghy);
        inter =        d0 * fmaf(a1, py0, -b1 * px0);
        inter = fmaf(  d1, -fmaf(b2, px1,  a2 * py1), inter);
        inter = fmaf(  d2,  fmaf(b1, px2, -a1 * py2), inter);
        inter = fmaf(  d3,  fmaf(b2, px3,  a2 * py3), inter);
    }

    // Half 2: gt edges vs pred box, t computed in pred's frame (t invariant);
    // each axis-aligned gt edge piece contributes ghx*ghy*Delta.
    {
        const float A  = cth * ghx, Dv = sth * ghx;
        const float Bq = sth * ghy, Ev = cth * ghy;
        const float Cc = fmaf(cth, cx,  sth * cy);
        const float Gf = fmaf(sth, cx, -cth * cy);
        const float g1 = A + Bq,  g2 = A - Bq;
        const float h1 = Ev - Dv, h2 = Ev + Dv;
        const float u0 =  g1 - Cc, v0 =  h1 + Gf;
        const float u1 = -g2 - Cc, v1 =  h2 + Gf;
        const float u2 = -g1 - Cc, v2 = -h1 + Gf;
        const float u3 =  g2 - Cc, v3 = -h2 + Gf;

        const float tA = A + A,   tD = Dv + Dv;
        const float tB = Bq + Bq, tE = Ev + Ev;
        const float rA = __builtin_amdgcn_rcpf(tA);
        const float rD = __builtin_amdgcn_rcpf(tD);
        const float rB = __builtin_amdgcn_rcpf(tB);
        const float rE = __builtin_amdgcn_rcpf(tE);

        float sq;
        sq  = edge_delta(u0, v0, -tA,  tD, -rA,  rD, phx, phy);
        sq += edge_delta(u1, v1, -tB, -tE, -rB, -rE, phx, phy);
        sq += edge_delta(u2, v2,  tA, -tD,  rA, -rD, phx, phy);
        sq += edge_delta(u3, v3,  tB,  tE,  rB,  rE, phx, phy);
        inter = fmaf(ghx * ghy, sq, inter);
    }

    const float za0 = paz - 0.5f * pdz, za1 = paz + 0.5f * pdz;
    const float zb0 = gaz - 0.5f * gdz, zb1 = gaz + 0.5f * gdz;
    const float zo  = fmaxf(fminf(za1, zb1) - fmaxf(za0, zb0), 0.f);
    const float iv  = inter * zo;
    const float va  = pdx * pdy * pdz;
    const float vb  = gdx * gdy * gdz;
    const float iou = __fdividef(iv, va + vb - iv + 1e-7f);
    const float target = 2.f * iou - 1.f;

    num = fmaf(m, fabsf(ip - target), num);
    den += m;
}

__global__ __launch_bounds__(TPB) void iou_main(
    const float* __restrict__ iou_pred,
    const int*   __restrict__ mask,
    const float* __restrict__ box_pred,   // [B,7,H,W]
    const float* __restrict__ box_gt,     // [B,H,W,7]
    float2* __restrict__ ws)              // [NBLK] block partials (num, den)
{
    __shared__ float rn[4], rd[4];

    const int tid = threadIdx.x;
    const int n0  = (blockIdx.x * TPB + tid) * NPT;   // 4 consecutive elements
    const int b   = n0 / HW_;
    const int hw  = n0 - b * HW_;                     // NPT-aligned

    // ---- issue ALL global loads upfront (16 x 16B in flight) ----
    const float* bp = box_pred + (size_t)b * 7 * HW_ + hw;
    F4 pc[7];
#pragma unroll
    for (int c = 0; c < 7; ++c)
        pc[c].v = *(const float4*)(bp + (size_t)c * HW_);   // dense coalesced

    float gtv[28];                                          // 7 aligned float4
    {
        const float4* g4 = (const float4*)(box_gt + (size_t)n0 * 7);
#pragma unroll
        for (int j = 0; j < 7; ++j)
            *(float4*)(gtv + 4 * j) = g4[j];
    }
    F4 ip4; ip4.v = *(const float4*)(iou_pred + n0);
    I4 mk4; mk4.v = *(const int4*)(mask + n0);

    // ---- compute 4 elements ----
    float num = 0.f, den = 0.f;
#pragma unroll
    for (int e = 0; e < NPT; ++e) {
        const float* g = gtv + 7 * e;
        iou_elem(pc[0].a[e], pc[1].a[e], pc[2].a[e],
                 pc[3].a[e], pc[4].a[e], pc[5].a[e], pc[6].a[e],
                 g[0], g[1], g[2], g[3], g[4], g[5], g[6],
                 ip4.a[e], (float)mk4.a[e], num, den);
    }

    // ---- wave(64) then cross-wave reduction ----
#pragma unroll
    for (int off = 32; off > 0; off >>= 1) {
        num += __shfl_down(num, off);
        den += __shfl_down(den, off);
    }
    if ((tid & 63) == 0) { rn[tid >> 6] = num; rd[tid >> 6] = den; }
    __syncthreads();
    if (tid == 0)
        ws[blockIdx.x] = make_float2(rn[0] + rn[1] + rn[2] + rn[3],
                                     rd[0] + rd[1] + rd[2] + rd[3]);
}

__global__ __launch_bounds__(TPB) void iou_fin(const float2* __restrict__ ws,
                                               float* __restrict__ out) {
    __shared__ float rn[4], rd[4];
    float sn = 0.f, sd = 0.f;
    for (int i = threadIdx.x; i < NBLK; i += TPB) {
        const float2 v = ws[i];
        sn += v.x;
        sd += v.y;
    }
#pragma unroll
    for (int off = 32; off > 0; off >>= 1) {
        sn += __shfl_down(sn, off);
        sd += __shfl_down(sd, off);
    }
    const int tid = threadIdx.x;
    if ((tid & 63) == 0) { rn[tid >> 6] = sn; rd[tid >> 6] = sd; }
    __syncthreads();
    if (tid == 0)
        out[0] = (rn[0] + rn[1] + rn[2] + rn[3]) /
                 (rd[0] + rd[1] + rd[2] + rd[3] + 1e-4f);
}

extern "C" void kernel_launch(void* const* d_in, const int* in_sizes, int n_in,
                              void* d_out, int out_size, void* d_ws, size_t ws_size,
                              hipStream_t stream) {
    const float* iou_pred = (const float*)d_in[0];
    const int*   mask     = (const int*)  d_in[1];
    // d_in[2] = ind (unused by the layer)
    const float* box_pred = (const float*)d_in[3];
    const float* box_gt   = (const float*)d_in[4];
    float*  out = (float*)d_out;
    float2* ws  = (float2*)d_ws;   // NBLK float2 partials, plain stores

    iou_main<<<NBLK, TPB, 0, stream>>>(iou_pred, mask, box_pred, box_gt, ws);
    iou_fin<<<1, TPB, 0, stream>>>(ws, out);
}